// Round 1
// baseline (199.898 us; speedup 1.0000x reference)
//
#include <hip/hip_runtime.h>
#include <hip/hip_bf16.h>

namespace {

constexpr int kVocab = 100000;
constexpr int kS     = 13;     // sequence / n_feat
constexpr int kH     = 128;    // hidden
constexpr int kNR    = 4;      // batch rows per set
constexpr int kBatch = 16384;
constexpr int kGrid  = 1024;
constexpr int kSetsPerBlk = (kBatch / kNR) / kGrid;  // 4

typedef __attribute__((ext_vector_type(8))) short bf16x8;
typedef __attribute__((ext_vector_type(4))) float f32x4;

__device__ __forceinline__ short f2b(float f) {
  __hip_bfloat16 h = __float2bfloat16(f);
  return __builtin_bit_cast(short, h);
}

// Fully fused: gather+pack -> QKV MFMA (wave==head, weights in registers) ->
// scores MFMA -> wave-parallel softmax -> column-sum weights -> V combine.
__global__ __launch_bounds__(256, 2)
void fsa_fused(const int* __restrict__ hs,
               const float* __restrict__ num_emb,
               const float* __restrict__ feat_emb,
               const float* __restrict__ Wq, const float* __restrict__ bq,
               const float* __restrict__ Wk, const float* __restrict__ bk,
               const float* __restrict__ Wv, const float* __restrict__ bv,
               float* __restrict__ out)
{
  // emb rows padded to 136 bf16 (272B stride) to break bank alignment (G4)
  __shared__ __align__(16) __hip_bfloat16 embS[kNR][16][136];
  // per-wave Q/K head-slice buffers, rows padded to 40 bf16 (80B = 5*16B)
  __shared__ __align__(16) __hip_bfloat16 qbuf[4][16][40];
  __shared__ __align__(16) __hip_bfloat16 kbuf[4][16][40];
  __shared__ __align__(16) float wbuf[4][16];

  const int tid  = threadIdx.x;
  const int lane = tid & 63;
  const int h    = tid >> 6;     // wave index == head index (head dim 32)
  const int l15  = lane & 15;
  const int g    = lane >> 4;

  // ---- persistent weight B-fragments: wave h needs only cols [32h,32h+32) ----
  // B[k][n] = W[n][k]; lane reads 8 consecutive f32 of W row n = 32h+16nt+l15.
  bf16x8 bfrag[3][2][4];   // [mat][nt][kk] = 96 VGPRs
  float  bias[3][2];
  {
    const float* Wmat[3] = {Wq, Wk, Wv};
    const float* bvec[3] = {bq, bk, bv};
#pragma unroll
    for (int m = 0; m < 3; ++m) {
#pragma unroll
      for (int nt = 0; nt < 2; ++nt) {
        const int n = 32*h + 16*nt + l15;
        bias[m][nt] = bvec[m][n];
#pragma unroll
        for (int kk = 0; kk < 4; ++kk) {
          const float* p = Wmat[m] + (size_t)n * kH + kk*32 + g*8;
          const float4 x0 = *(const float4*)p;
          const float4 x1 = *(const float4*)(p + 4);
          bf16x8 fr;
          fr[0]=f2b(x0.x); fr[1]=f2b(x0.y); fr[2]=f2b(x0.z); fr[3]=f2b(x0.w);
          fr[4]=f2b(x1.x); fr[5]=f2b(x1.y); fr[6]=f2b(x1.z); fr[7]=f2b(x1.w);
          bfrag[m][nt][kk] = fr;
        }
      }
    }
  }

  // zero pad rows (s = 13..15) of embS once; they stay zero (gather only writes s<13)
  for (int i = tid; i < kNR*3*136; i += 256) {
    const int r  = i / (3*136);
    const int rm = i % (3*136);
    embS[r][13 + rm/136][rm%136] = __float2bfloat16(0.0f);
  }

  for (int it = 0; it < kSetsPerBlk; ++it) {
    const int row0 = (blockIdx.x * kSetsPerBlk + it) * kNR;
    __syncthreads();  // prev set consumed; pad zeroing visible on first iter

    // ---- cooperative gather: emb = (num_emb[idx] + feat)*0.5 -> bf16 LDS ----
    for (int c = tid; c < kNR*kS*32; c += 256) {
      const int p = c >> 5;          // (row,s) pair: 32 lanes per 512B segment
      const int j = c & 31;          // float4 column
      const int r = p / kS;
      const int s = p % kS;
      int ix = hs[(row0 + r)*kS + s];
      ix = (ix > -1) ? ix : (kVocab - 1);
      const float4 nv = *(const float4*)(num_emb + (size_t)ix*kH + j*4);
      const float4 fv = *(const float4*)(feat_emb + s*kH + j*4);
      short4 ev;
      ev.x = f2b((nv.x + fv.x)*0.5f);
      ev.y = f2b((nv.y + fv.y)*0.5f);
      ev.z = f2b((nv.z + fv.z)*0.5f);
      ev.w = f2b((nv.w + fv.w)*0.5f);
      *(short4*)(&embS[r][s][j*4]) = ev;
    }
    __syncthreads();

    // ---- per-row compute; wave h owns head h ----
#pragma unroll 1
    for (int r = 0; r < kNR; ++r) {
      // A-frags: A[s][k], s = l15, k = 32*kk + 8*g + i  (16B contiguous)
      bf16x8 a[4];
#pragma unroll
      for (int kk = 0; kk < 4; ++kk)
        a[kk] = *(const bf16x8*)(&embS[r][l15][kk*32 + g*8]);

      const f32x4 zero4 = {0.f, 0.f, 0.f, 0.f};
      f32x4 accq[2], acck[2], accv[2];
#pragma unroll
      for (int nt = 0; nt < 2; ++nt) {
        f32x4 aq = zero4, ak = zero4, av = zero4;
#pragma unroll
        for (int kk = 0; kk < 4; ++kk) {
          aq = __builtin_amdgcn_mfma_f32_16x16x32_bf16(a[kk], bfrag[0][nt][kk], aq, 0,0,0);
          ak = __builtin_amdgcn_mfma_f32_16x16x32_bf16(a[kk], bfrag[1][nt][kk], ak, 0,0,0);
          av = __builtin_amdgcn_mfma_f32_16x16x32_bf16(a[kk], bfrag[2][nt][kk], av, 0,0,0);
        }
        accq[nt] = aq; acck[nt] = ak; accv[nt] = av;
      }

      // D layout: row s = 4*g+j, col(in-head) d = 16*nt+l15. Publish Q,K to LDS.
#pragma unroll
      for (int nt = 0; nt < 2; ++nt)
#pragma unroll
        for (int j = 0; j < 4; ++j) {
          qbuf[h][4*g + j][16*nt + l15] = __float2bfloat16(accq[nt][j] + bias[0][nt]);
          kbuf[h][4*g + j][16*nt + l15] = __float2bfloat16(acck[nt][j] + bias[1][nt]);
        }
#pragma unroll
      for (int nt = 0; nt < 2; ++nt)
#pragma unroll
        for (int j = 0; j < 4; ++j)
          accv[nt][j] += bias[2][nt];

      __syncthreads();  // publish qbuf/kbuf (cross-lane)

      // scores S = Q_h * K_h^T : one MFMA, K-dim = head_dim = 32
      // A: Q[l15][8g+i]   B: K^T[8g+i][l15] = K[l15][8g+i]  (same read pattern)
      const bf16x8 aqf = *(const bf16x8*)(&qbuf[h][l15][g*8]);
      const bf16x8 bkf = *(const bf16x8*)(&kbuf[h][l15][g*8]);
      f32x4 sc = __builtin_amdgcn_mfma_f32_16x16x32_bf16(aqf, bkf, zero4, 0,0,0);

      // softmax over t (= l15) within 16-lane groups; rows s = 4g+j
      const float rsc = 0.17677669529663687f;  // 1/sqrt(32)
      const bool tval = (l15 < 13);
      float wsum = 0.f;
#pragma unroll
      for (int j = 0; j < 4; ++j) {
        float s = tval ? sc[j]*rsc : -1e30f;
        float m = s;
#pragma unroll
        for (int d = 1; d < 16; d <<= 1)
          m = fmaxf(m, __shfl_xor(m, d, 16));
        float e = __expf(s - m);
        float su = e;
#pragma unroll
        for (int d = 1; d < 16; d <<= 1)
          su += __shfl_xor(su, d, 16);
        float pv = e / su;
        if (4*g + j >= 13) pv = 0.f;   // exclude pad s-rows from column sum
        wsum += pv;
      }
      // column sums across the four 16-lane groups -> w[t] in every lane
      wsum += __shfl_xor(wsum, 16, 64);
      wsum += __shfl_xor(wsum, 32, 64);
      wsum *= (1.0f/13.0f);            // fold mean over s into w
      if (g == 0) wbuf[h][l15] = tval ? wsum : 0.f;
      __syncthreads();  // publish wbuf

      // lane needs w[s'] for s' = 4g..4g+3 -> one 16B read
      const f32x4 wv = *(const f32x4*)(&wbuf[h][4*g]);

      // out[n] = sum_t w[t] * V[t][n]; V still in D-frags
      float o0 = wv[0]*accv[0][0] + wv[1]*accv[0][1] + wv[2]*accv[0][2] + wv[3]*accv[0][3];
      float o1 = wv[0]*accv[1][0] + wv[1]*accv[1][1] + wv[2]*accv[1][2] + wv[3]*accv[1][3];
      o0 += __shfl_xor(o0, 16, 64); o0 += __shfl_xor(o0, 32, 64);
      o1 += __shfl_xor(o1, 16, 64); o1 += __shfl_xor(o1, 32, 64);
      if (lane < 32)
        out[(size_t)(row0 + r)*kH + 32*h + lane] = (lane < 16) ? o0 : o1;
    }
  }
}

} // namespace

extern "C" void kernel_launch(void* const* d_in, const int* in_sizes, int n_in,
                              void* d_out, int out_size, void* d_ws, size_t ws_size,
                              hipStream_t stream) {
  const int*   hs = (const int*)  d_in[0];
  const float* ne = (const float*)d_in[1];
  const float* fe = (const float*)d_in[2];
  const float* Wq = (const float*)d_in[3];
  const float* bq = (const float*)d_in[4];
  const float* Wk = (const float*)d_in[5];
  const float* bk = (const float*)d_in[6];
  const float* Wv = (const float*)d_in[7];
  const float* bv = (const float*)d_in[8];
  float* out = (float*)d_out;
  fsa_fused<<<dim3(kGrid), dim3(256), 0, stream>>>(hs, ne, fe, Wq, bq, Wk, bk, Wv, bv, out);
}